// Round 2
// baseline (491.391 us; speedup 1.0000x reference)
//
#include <hip/hip_runtime.h>
#include <stdint.h>

#define NN   8192
#define DIN  256
#define DOUT 32

#define PPART (NN * DOUT + 320)   // padded stride (floats) for logits partials
#define PP4   (DOUT * DIN + 320)  // padded stride (floats) for pooling partials
#define NBLK_T 256                // tail-kernel grid (co-resident: 64K threads, 17KB LDS)

typedef short bf16x8 __attribute__((ext_vector_type(8)));
typedef float f32x16 __attribute__((ext_vector_type(16)));

union BF8 { uint32_t u[4]; bf16x8 v; };

// Split fp32 pair into packed bf16 hi (truncated top 16 bits) and bf16 lo (residual).
__device__ __forceinline__ void split_pair(float a, float b, uint32_t& hp, uint32_t& lp) {
    uint32_t ua = __float_as_uint(a), ub = __float_as_uint(b);
    hp = (ua >> 16) | (ub & 0xffff0000u);
    float la = a - __uint_as_float(ua & 0xffff0000u);
    float lb = b - __uint_as_float(ub & 0xffff0000u);
    lp = (__float_as_uint(la) >> 16) | (__float_as_uint(lb) & 0xffff0000u);
}

// Device-scope grid barrier among NBLK_T co-resident blocks. Counter must be
// pre-zeroed (done in k1_support each iteration; stream order guarantees it).
__device__ __forceinline__ void grid_barrier(int* bar) {
    __syncthreads();
    if (threadIdx.x == 0) {
        __threadfence();   // agent-scope release: flush local L2 (cross-XCD visibility)
        __hip_atomic_fetch_add(bar, 1, __ATOMIC_RELAXED, __HIP_MEMORY_SCOPE_AGENT);
        while (__hip_atomic_load(bar, __ATOMIC_RELAXED, __HIP_MEMORY_SCOPE_AGENT) < NBLK_T) {}
        __threadfence();   // agent-scope acquire: invalidate stale lines
    }
    __syncthreads();
}

// ---------------------------------------------------------------------------
// K1: support = X @ W (fp32 accumulate), emitted as bf16 hi/lo MFMA B-fragments.
// Also zeroes the grid-barrier counters for the tail kernel (workspace is
// poisoned between iterations; k1 -> k2 -> kt stream order makes this safe).
__global__ __launch_bounds__(256) void k1_support(
    const float* __restrict__ X, const float* __restrict__ W,
    unsigned short* __restrict__ hi_frag, unsigned short* __restrict__ lo_frag,
    int* __restrict__ bars)
{
    __shared__ float Xs[32 * 256];   // 32 KB
    int t = threadIdx.x;
    int kbase = blockIdx.x * 32;

    if (blockIdx.x == 0 && t < 2) bars[t] = 0;

    const float4* Xg = (const float4*)(X + (size_t)kbase * DIN);
    float4* Xs4 = (float4*)Xs;
#pragma unroll
    for (int p = 0; p < 8; ++p) Xs4[p * 256 + t] = Xg[p * 256 + t];
    __syncthreads();

    int c = t & 31;
    int q = t >> 5;
    int kb2  = q >> 2;
    int half = (q >> 1) & 1;
    int j4   = q & 1;
    int krow0 = kb2 * 16 + half * 8 + j4 * 4;

    float acc[4] = {0.f, 0.f, 0.f, 0.f};
    for (int d = 0; d < 256; ++d) {
        float w = W[d * 32 + c];
#pragma unroll
        for (int jj = 0; jj < 4; ++jj)
            acc[jj] += Xs[(krow0 + jj) * 256 + d] * w;
    }

    uint32_t h01, l01, h23, l23;
    split_pair(acc[0], acc[1], h01, l01);
    split_pair(acc[2], acc[3], h23, l23);

    int ks = (kbase >> 4) + kb2;
    size_t elembase = (size_t)ks * 512 + (size_t)(half * 32 + c) * 8 + j4 * 4;
    *(uint2*)(hi_frag + elembase) = make_uint2(h01, h23);
    *(uint2*)(lo_frag + elembase) = make_uint2(l01, l23);
}

// ---------------------------------------------------------------------------
// K2: partial logits via split-bf16 MFMA, LDS-staged adj. UNCHANGED from the
// previous round (already >=4 blocks/CU, reg-destined prefetch overlaps MFMA).
__global__ __launch_bounds__(512) void k2_logits(
    const float* __restrict__ adj,
    const unsigned short* __restrict__ hi_frag,
    const unsigned short* __restrict__ lo_frag,
    float* __restrict__ part)     // 4 partials, stride PPART floats
{
    __shared__ __align__(16) float tile[32 * 260];   // 33.3 KB, padded rows (1040 B)
    int t = threadIdx.x;
    int lane = t & 63, wv = t >> 6;
    int row0 = blockIdx.x * 32;
    size_t col0 = (size_t)blockIdx.y * 2048;

    f32x16 acc;
#pragma unroll
    for (int i = 0; i < 16; ++i) acc[i] = 0.f;

    int r  = lane & 31;
    int hs = lane >> 5;
    int tl0 = blockIdx.x & 7;    // rotated tile start

    const float* asrc = adj + (size_t)(row0 + wv) * NN + col0 + lane * 4;

    float4 pref[4];
    {   // prologue: stage tile tl0
#pragma unroll
        for (int p = 0; p < 4; ++p)
            pref[p] = *(const float4*)(asrc + (size_t)(8 * p) * NN + tl0 * 256);
#pragma unroll
        for (int p = 0; p < 4; ++p)
            *(float4*)((char*)tile + (wv + 8 * p) * 1040 + lane * 16) = pref[p];
    }

    for (int tt = 0; tt < 8; ++tt) {
        int tl  = (tt + tl0) & 7;
        int tln = (tt + 1 + tl0) & 7;
        if (tt < 7) {   // prefetch next tile into registers
#pragma unroll
            for (int p = 0; p < 4; ++p)
                pref[p] = *(const float4*)(asrc + (size_t)(8 * p) * NN + tln * 256);
        }
        __syncthreads();
#pragma unroll
        for (int ss = 0; ss < 2; ++ss) {
            int s = 2 * wv + ss;
            const float4* ap = (const float4*)((const char*)tile + r * 1040 + s * 64 + hs * 32);
            float4 a0 = ap[0];
            float4 a1 = ap[1];
            int ks = (int)blockIdx.y * 128 + tl * 16 + s;
            BF8 bh, bl, ah, al;
            bh.v = *(const bf16x8*)(hi_frag + (size_t)ks * 512 + lane * 8);
            bl.v = *(const bf16x8*)(lo_frag + (size_t)ks * 512 + lane * 8);
            split_pair(a0.x, a0.y, ah.u[0], al.u[0]);
            split_pair(a0.z, a0.w, ah.u[1], al.u[1]);
            split_pair(a1.x, a1.y, ah.u[2], al.u[2]);
            split_pair(a1.z, a1.w, ah.u[3], al.u[3]);
            acc = __builtin_amdgcn_mfma_f32_32x32x16_bf16(ah.v, bh.v, acc, 0, 0, 0);
            acc = __builtin_amdgcn_mfma_f32_32x32x16_bf16(ah.v, bl.v, acc, 0, 0, 0);
            acc = __builtin_amdgcn_mfma_f32_32x32x16_bf16(al.v, bh.v, acc, 0, 0, 0);
        }
        if (tt < 7) {
            __syncthreads();
#pragma unroll
            for (int p = 0; p < 4; ++p)
                *(float4*)((char*)tile + (wv + 8 * p) * 1040 + lane * 16) = pref[p];
        }
    }

    __syncthreads();
    float* red = tile;
#pragma unroll
    for (int g = 0; g < 16; ++g) red[wv * 1024 + lane * 16 + g] = acc[g];
    __syncthreads();

    float* pdst = part + (size_t)blockIdx.y * PPART + (size_t)row0 * 32;
    for (int a = t; a < 1024; a += 512) {
        int row = a >> 5, colc = a & 31;
        int l = colc + 32 * ((row >> 2) & 1);
        int g = (row & 3) | ((row >> 3) << 2);
        float ssum = 0.f;
#pragma unroll
        for (int w8 = 0; w8 < 8; ++w8) ssum += red[w8 * 1024 + l * 16 + g];
        pdst[a] = ssum;
    }
}

// ---------------------------------------------------------------------------
// KT: fused tail = K3a + K3b + K4 + K5 with 2 grid barriers.
// 256 blocks x 256 threads. Block b owns logit rows [b*32, b*32+32): the
// summed logits and their exp() live in REGISTERS across the softmax phases
// (no logits_sum / e_buf global round-trips).
__global__ __launch_bounds__(256) void kt_tail(
    const float* __restrict__ part, const float* __restrict__ X,
    float* __restrict__ Mpart, float* __restrict__ Spart,
    float* __restrict__ p4, float* __restrict__ out, int* __restrict__ bars)
{
    __shared__ float red[256 * 4];   // 4 KB scratch for reductions
    __shared__ float As[32 * 32];    // 4 KB: exp(logit) for this block's 32 rows
    __shared__ float Xs[8 * 256];    // 8 KB: X staging for pooling
    __shared__ float sred[256];      // 1 KB: Spart reduction (phase C)
    int t = threadIdx.x;
    int b = blockIdx.x;

    // ---- Phase A: sum the 4 k-partials (regs), per-block column maxes ----
    size_t f = (size_t)b * 256 + t;   // float4 index; floats b*1024 + 4t
    float4 v = make_float4(0.f, 0.f, 0.f, 0.f);
#pragma unroll
    for (int pp = 0; pp < 4; ++pp) {
        int p = (pp + b) & 3;   // rotated partial order
        float4 u = ((const float4*)(part + (size_t)p * PPART))[f];
        v.x += u.x; v.y += u.y; v.z += u.z; v.w += u.w;
    }
    red[t * 4 + 0] = v.x; red[t * 4 + 1] = v.y;
    red[t * 4 + 2] = v.z; red[t * 4 + 3] = v.w;
    __syncthreads();
    for (int s = 128; s >= 8; s >>= 1) {
        if (t < s)
#pragma unroll
            for (int j = 0; j < 4; ++j)
                red[t * 4 + j] = fmaxf(red[t * 4 + j], red[(t + s) * 4 + j]);
        __syncthreads();
    }
    if (t < 8)
#pragma unroll
        for (int j = 0; j < 4; ++j)
            Mpart[b * 32 + t * 4 + j] = red[t * 4 + j];

    grid_barrier(bars + 0);

    // ---- Phase B: fold global col maxes, exp in regs, col sums, pooling ----
    int c = t & 31, g0 = t >> 5;
    {
        float m = -3.4e38f;
#pragma unroll
        for (int gg = 0; gg < 32; ++gg)
            m = fmaxf(m, Mpart[(g0 * 32 + gg) * 32 + c]);
        red[t] = m;
    }
    __syncthreads();
    for (int s = 128; s >= 32; s >>= 1) {
        if (t < s) red[t] = fmaxf(red[t], red[t + s]);
        __syncthreads();
    }
    float m0 = red[(4 * t + 0) & 31], m1 = red[(4 * t + 1) & 31];
    float m2 = red[(4 * t + 2) & 31], m3 = red[(4 * t + 3) & 31];
    __syncthreads();   // before red reuse

    v.x = __expf(v.x - m0); v.y = __expf(v.y - m1);
    v.z = __expf(v.z - m2); v.w = __expf(v.w - m3);
    // scatter into As[row][col]: row = t>>3, cols = (4t+j)&31
    {
        int row = t >> 3, cb = (4 * t) & 31;
        As[row * 32 + cb]     = v.x;
        As[row * 32 + cb + 1] = v.y;
        As[row * 32 + cb + 2] = v.z;
        As[row * 32 + cb + 3] = v.w;
    }
    red[t * 4 + 0] = v.x; red[t * 4 + 1] = v.y;
    red[t * 4 + 2] = v.z; red[t * 4 + 3] = v.w;
    __syncthreads();
    for (int s = 128; s >= 8; s >>= 1) {
        if (t < s)
#pragma unroll
            for (int j = 0; j < 4; ++j)
                red[t * 4 + j] += red[(t + s) * 4 + j];
        __syncthreads();
    }
    if (t < 8)
#pragma unroll
        for (int j = 0; j < 4; ++j)
            Spart[b * 32 + t * 4 + j] = red[t * 4 + j];

    // pooling: p4[b] = e(32 rows)^T @ X(32 rows), X staged 8 rows at a time
    int dg = t >> 5;
    int ibase = b * 32;
    float acc[32];
#pragma unroll
    for (int i = 0; i < 32; ++i) acc[i] = 0.f;

    for (int rnd = 0; rnd < 4; ++rnd) {
        __syncthreads();
        const float4* Xg = (const float4*)(X + (size_t)(ibase + rnd * 8) * DIN);
        float4* Xs4 = (float4*)Xs;
        Xs4[t]       = Xg[t];
        Xs4[256 + t] = Xg[256 + t];
        __syncthreads();
#pragma unroll
        for (int i2 = 0; i2 < 8; ++i2) {
            float a = As[(rnd * 8 + i2) * 32 + c];
#pragma unroll
            for (int dd = 0; dd < 32; ++dd)
                acc[dd] += a * Xs[i2 * 256 + dg * 32 + dd];
        }
    }
    {
        float* dst = p4 + (size_t)b * PP4 + (size_t)c * 256 + dg * 32;
#pragma unroll
        for (int q = 0; q < 8; ++q)
            ((float4*)dst)[q] = make_float4(acc[q * 4], acc[q * 4 + 1],
                                            acc[q * 4 + 2], acc[q * 4 + 3]);
    }

    grid_barrier(bars + 1);

    // ---- Phase C: reduce 256 pooling partials + total S, scale, write out ----
    int c_out = b >> 3;   // all 32 outputs of this block share one cluster
    sred[t] = Spart[t * 32 + c_out];

    int j = b * 32 + (t & 31);
    float a = 0.f;
#pragma unroll
    for (int gg = 0; gg < 32; ++gg) {
        int g = (g0 * 32 + gg + b) & 255;   // rotated start
        a += p4[(size_t)g * PP4 + j];
    }
    red[t] = a;
    __syncthreads();
    for (int s = 128; s >= 32; s >>= 1) {
        if (t < s) { red[t] += red[t + s]; sred[t] += sred[t + s]; }
        __syncthreads();
    }
    if (t < 32) {
        float sv = sred[t];
#pragma unroll
        for (int off = 16; off >= 1; off >>= 1) sv += __shfl_xor(sv, off);
        out[b * 32 + t] = red[t] / sv;
    }
}

// ---------------------------------------------------------------------------
extern "C" void kernel_launch(void* const* d_in, const int* in_sizes, int n_in,
                              void* d_out, int out_size, void* d_ws, size_t ws_size,
                              hipStream_t stream) {
    const float* X   = (const float*)d_in[0];   // [8192, 256]
    const float* adj = (const float*)d_in[1];   // [8192, 8192]
    const float* W   = (const float*)d_in[2];   // [256, 32]
    // d_in[3] = b: ignored — softmax over dim 0 is invariant to per-column shift.
    float* out = (float*)d_out;                 // [32, 256]

    char* w = (char*)d_ws;
    unsigned short* hi_frag = (unsigned short*)w;                        // 512 KB
    unsigned short* lo_frag = (unsigned short*)(w + 512 * 1024);         // 512 KB
    size_t off = 1024 * 1024;
    float* part = (float*)(w + off);   off += (size_t)4 * PPART * sizeof(float);
    float* Mpart = (float*)(w + off);  off += 256 * 32 * sizeof(float);
    float* Spart = (float*)(w + off);  off += 256 * 32 * sizeof(float);
    float* p4 = (float*)(w + off);     off += (size_t)256 * PP4 * sizeof(float);
    off = (off + 127) & ~(size_t)127;
    int* bars = (int*)(w + off);       off += 128;

    k1_support<<<NN / 32, 256, 0, stream>>>(X, W, hi_frag, lo_frag, bars);
    k2_logits<<<dim3(NN / 32, 4), 512, 0, stream>>>(adj, hi_frag, lo_frag, part);
    kt_tail<<<NBLK_T, 256, 0, stream>>>(part, X, Mpart, Spart, p4, out, bars);
}

// Round 3
// 448.195 us; speedup vs baseline: 1.0964x; 1.0964x over previous
//
#include <hip/hip_runtime.h>
#include <stdint.h>

#define NN   8192
#define DIN  256
#define DOUT 32

#define PPART (NN * DOUT + 320)   // padded stride (floats) for logits partials
#define PP4   (DOUT * DIN + 320)  // padded stride (floats) for pooling partials

typedef short bf16x8 __attribute__((ext_vector_type(8)));
typedef float f32x16 __attribute__((ext_vector_type(16)));

union BF8 { uint32_t u[4]; bf16x8 v; };

// Split fp32 pair into packed bf16 hi (truncated top 16 bits) and bf16 lo (residual).
__device__ __forceinline__ void split_pair(float a, float b, uint32_t& hp, uint32_t& lp) {
    uint32_t ua = __float_as_uint(a), ub = __float_as_uint(b);
    hp = (ua >> 16) | (ub & 0xffff0000u);
    float la = a - __uint_as_float(ua & 0xffff0000u);
    float lb = b - __uint_as_float(ub & 0xffff0000u);
    lp = (__float_as_uint(la) >> 16) | (__float_as_uint(lb) & 0xffff0000u);
}

// ---------------------------------------------------------------------------
// K1: support = X @ W (fp32 accumulate), emitted as bf16 hi/lo MFMA B-fragments.
// B-frag layout (v_mfma_f32_32x32x16_bf16): lane l holds B[k=(l>>5)*8+j][n=l&31].
__global__ __launch_bounds__(256) void k1_support(
    const float* __restrict__ X, const float* __restrict__ W,
    unsigned short* __restrict__ hi_frag, unsigned short* __restrict__ lo_frag)
{
    __shared__ float Xs[32 * 256];   // 32 KB
    int t = threadIdx.x;
    int kbase = blockIdx.x * 32;

    const float4* Xg = (const float4*)(X + (size_t)kbase * DIN);
    float4* Xs4 = (float4*)Xs;
#pragma unroll
    for (int p = 0; p < 8; ++p) Xs4[p * 256 + t] = Xg[p * 256 + t];
    __syncthreads();

    int c = t & 31;
    int q = t >> 5;
    int kb2  = q >> 2;
    int half = (q >> 1) & 1;
    int j4   = q & 1;
    int krow0 = kb2 * 16 + half * 8 + j4 * 4;

    float acc[4] = {0.f, 0.f, 0.f, 0.f};
    for (int d = 0; d < 256; ++d) {
        float w = W[d * 32 + c];
#pragma unroll
        for (int jj = 0; jj < 4; ++jj)
            acc[jj] += Xs[(krow0 + jj) * 256 + d] * w;
    }

    uint32_t h01, l01, h23, l23;
    split_pair(acc[0], acc[1], h01, l01);
    split_pair(acc[2], acc[3], h23, l23);

    int ks = (kbase >> 4) + kb2;
    size_t elembase = (size_t)ks * 512 + (size_t)(half * 32 + c) * 8 + j4 * 4;
    *(uint2*)(hi_frag + elembase) = make_uint2(h01, h23);
    *(uint2*)(lo_frag + elembase) = make_uint2(l01, l23);
}

// ---------------------------------------------------------------------------
// K2: partial logits via split-bf16 MFMA, LDS-staged adj. Unchanged (best-
// verified structure: 4 blocks/CU, reg-destined prefetch overlaps MFMA phase).
__global__ __launch_bounds__(512) void k2_logits(
    const float* __restrict__ adj,
    const unsigned short* __restrict__ hi_frag,
    const unsigned short* __restrict__ lo_frag,
    float* __restrict__ part)     // 4 partials, stride PPART floats
{
    __shared__ __align__(16) float tile[32 * 260];   // 33.3 KB, padded rows (1040 B)
    int t = threadIdx.x;
    int lane = t & 63, wv = t >> 6;
    int row0 = blockIdx.x * 32;
    size_t col0 = (size_t)blockIdx.y * 2048;

    f32x16 acc;
#pragma unroll
    for (int i = 0; i < 16; ++i) acc[i] = 0.f;

    int r  = lane & 31;
    int hs = lane >> 5;
    int tl0 = blockIdx.x & 7;    // rotated tile start

    const float* asrc = adj + (size_t)(row0 + wv) * NN + col0 + lane * 4;

    float4 pref[4];
    {   // prologue: stage tile tl0
#pragma unroll
        for (int p = 0; p < 4; ++p)
            pref[p] = *(const float4*)(asrc + (size_t)(8 * p) * NN + tl0 * 256);
#pragma unroll
        for (int p = 0; p < 4; ++p)
            *(float4*)((char*)tile + (wv + 8 * p) * 1040 + lane * 16) = pref[p];
    }

    for (int tt = 0; tt < 8; ++tt) {
        int tl  = (tt + tl0) & 7;
        int tln = (tt + 1 + tl0) & 7;
        if (tt < 7) {   // prefetch next tile into registers
#pragma unroll
            for (int p = 0; p < 4; ++p)
                pref[p] = *(const float4*)(asrc + (size_t)(8 * p) * NN + tln * 256);
        }
        __syncthreads();
#pragma unroll
        for (int ss = 0; ss < 2; ++ss) {
            int s = 2 * wv + ss;
            const float4* ap = (const float4*)((const char*)tile + r * 1040 + s * 64 + hs * 32);
            float4 a0 = ap[0];
            float4 a1 = ap[1];
            int ks = (int)blockIdx.y * 128 + tl * 16 + s;
            BF8 bh, bl, ah, al;
            bh.v = *(const bf16x8*)(hi_frag + (size_t)ks * 512 + lane * 8);
            bl.v = *(const bf16x8*)(lo_frag + (size_t)ks * 512 + lane * 8);
            split_pair(a0.x, a0.y, ah.u[0], al.u[0]);
            split_pair(a0.z, a0.w, ah.u[1], al.u[1]);
            split_pair(a1.x, a1.y, ah.u[2], al.u[2]);
            split_pair(a1.z, a1.w, ah.u[3], al.u[3]);
            acc = __builtin_amdgcn_mfma_f32_32x32x16_bf16(ah.v, bh.v, acc, 0, 0, 0);
            acc = __builtin_amdgcn_mfma_f32_32x32x16_bf16(ah.v, bl.v, acc, 0, 0, 0);
            acc = __builtin_amdgcn_mfma_f32_32x32x16_bf16(al.v, bh.v, acc, 0, 0, 0);
        }
        if (tt < 7) {
            __syncthreads();
#pragma unroll
            for (int p = 0; p < 4; ++p)
                *(float4*)((char*)tile + (wv + 8 * p) * 1040 + lane * 16) = pref[p];
        }
    }

    __syncthreads();
    float* red = tile;
#pragma unroll
    for (int g = 0; g < 16; ++g) red[wv * 1024 + lane * 16 + g] = acc[g];
    __syncthreads();

    float* pdst = part + (size_t)blockIdx.y * PPART + (size_t)row0 * 32;
    for (int a = t; a < 1024; a += 512) {
        int row = a >> 5, colc = a & 31;
        int l = colc + 32 * ((row >> 2) & 1);
        int g = (row & 3) | ((row >> 3) << 2);
        float ssum = 0.f;
#pragma unroll
        for (int w8 = 0; w8 < 8; ++w8) ssum += red[w8 * 1024 + l * 16 + g];
        pdst[a] = ssum;
    }
}

// ---------------------------------------------------------------------------
// T1: sum the 4 k-partials -> logits_sum; per-block column maxes. 256 blocks.
__global__ __launch_bounds__(256) void t1_sum_max(
    const float* __restrict__ part, float* __restrict__ logits_sum,
    float* __restrict__ Mpart)     // [256][32]
{
    __shared__ float red[256 * 4];
    int t = threadIdx.x;
    size_t f = (size_t)blockIdx.x * 256 + t;   // float4 index

    float4 v = make_float4(0.f, 0.f, 0.f, 0.f);
#pragma unroll
    for (int pp = 0; pp < 4; ++pp) {
        int p = (pp + blockIdx.x) & 3;   // rotated partial order
        float4 u = ((const float4*)(part + (size_t)p * PPART))[f];
        v.x += u.x; v.y += u.y; v.z += u.z; v.w += u.w;
    }
    ((float4*)logits_sum)[f] = v;

    red[t * 4 + 0] = v.x; red[t * 4 + 1] = v.y;
    red[t * 4 + 2] = v.z; red[t * 4 + 3] = v.w;
    __syncthreads();
    for (int s = 128; s >= 8; s >>= 1) {
        if (t < s)
#pragma unroll
            for (int j = 0; j < 4; ++j)
                red[t * 4 + j] = fmaxf(red[t * 4 + j], red[(t + s) * 4 + j]);
        __syncthreads();
    }
    if (t < 8)
#pragma unroll
        for (int j = 0; j < 4; ++j)
            Mpart[blockIdx.x * 32 + t * 4 + j] = red[t * 4 + j];
}

// ---------------------------------------------------------------------------
// T2: fused exp + pooling. Fold global col maxes (redundantly per block),
// e = exp(logit - M) kept in regs -> LDS (NO e_buf round-trip), column sums
// -> Spart, then pool p4[b] = e^T @ X over this block's 32 rows. 256 blocks.
__global__ __launch_bounds__(256) void t2_exp_pool(
    const float* __restrict__ logits_sum, const float* __restrict__ Mpart,
    const float* __restrict__ X, float* __restrict__ Spart,
    float* __restrict__ p4)    // 256 partials, stride PP4 floats
{
    __shared__ float red[256 * 4];   // 4 KB reduction scratch
    __shared__ float As[32 * 32];    // 4 KB: exp(logit) for this block's rows
    __shared__ float Xs[8 * 256];    // 8 KB: X staging
    int t = threadIdx.x;
    int b = blockIdx.x;
    int c = t & 31, g0 = t >> 5;

    // fold global column maxes from Mpart (8 KB, L2-resident)
    {
        float m = -3.4e38f;
#pragma unroll
        for (int gg = 0; gg < 32; ++gg)
            m = fmaxf(m, Mpart[(g0 * 32 + gg) * 32 + c]);
        red[t] = m;
    }
    __syncthreads();
    for (int s = 128; s >= 32; s >>= 1) {
        if (t < s) red[t] = fmaxf(red[t], red[t + s]);
        __syncthreads();
    }
    float m0 = red[(4 * t + 0) & 31], m1 = red[(4 * t + 1) & 31];
    float m2 = red[(4 * t + 2) & 31], m3 = red[(4 * t + 3) & 31];
    __syncthreads();   // before red reuse

    size_t f = (size_t)b * 256 + t;
    float4 v = ((const float4*)logits_sum)[f];
    v.x = __expf(v.x - m0); v.y = __expf(v.y - m1);
    v.z = __expf(v.z - m2); v.w = __expf(v.w - m3);
    // scatter into As[row][col]: row = t>>3, cols = (4t+j)&31
    {
        int row = t >> 3, cb = (4 * t) & 31;
        As[row * 32 + cb]     = v.x;
        As[row * 32 + cb + 1] = v.y;
        As[row * 32 + cb + 2] = v.z;
        As[row * 32 + cb + 3] = v.w;
    }
    red[t * 4 + 0] = v.x; red[t * 4 + 1] = v.y;
    red[t * 4 + 2] = v.z; red[t * 4 + 3] = v.w;
    __syncthreads();
    for (int s = 128; s >= 8; s >>= 1) {
        if (t < s)
#pragma unroll
            for (int j = 0; j < 4; ++j)
                red[t * 4 + j] += red[(t + s) * 4 + j];
        __syncthreads();
    }
    if (t < 8)
#pragma unroll
        for (int j = 0; j < 4; ++j)
            Spart[b * 32 + t * 4 + j] = red[t * 4 + j];

    // pooling: p4[b] = e(32 rows)^T @ X(32 rows), X staged 8 rows at a time
    int dg = t >> 5;
    int ibase = b * 32;
    float acc[32];
#pragma unroll
    for (int i = 0; i < 32; ++i) acc[i] = 0.f;

    for (int rnd = 0; rnd < 4; ++rnd) {
        __syncthreads();
        const float4* Xg = (const float4*)(X + (size_t)(ibase + rnd * 8) * DIN);
        float4* Xs4 = (float4*)Xs;
        Xs4[t]       = Xg[t];
        Xs4[256 + t] = Xg[256 + t];
        __syncthreads();
#pragma unroll
        for (int i2 = 0; i2 < 8; ++i2) {
            float a = As[(rnd * 8 + i2) * 32 + c];
#pragma unroll
            for (int dd = 0; dd < 32; ++dd)
                acc[dd] += a * Xs[i2 * 256 + dg * 32 + dd];
        }
    }
    float* dst = p4 + (size_t)b * PP4 + (size_t)c * 256 + dg * 32;
#pragma unroll
    for (int q = 0; q < 8; ++q)
        ((float4*)dst)[q] = make_float4(acc[q * 4], acc[q * 4 + 1],
                                        acc[q * 4 + 2], acc[q * 4 + 3]);
}

// ---------------------------------------------------------------------------
// T3: reduce 256 pooling partials + total S, scale by 1/S[cluster] -> out.
__global__ __launch_bounds__(256) void t3_reduce(
    const float* __restrict__ p4, const float* __restrict__ Spart,
    float* __restrict__ out)
{
    __shared__ float red[256];
    __shared__ float sred[256];
    int t = threadIdx.x;
    int c_out = blockIdx.x >> 3;     // all 32 outputs of this block share one cluster

    sred[t] = Spart[t * 32 + c_out];

    int j = blockIdx.x * 32 + (t & 31);
    int g0 = t >> 5;
    float a = 0.f;
#pragma unroll
    for (int gg = 0; gg < 32; ++gg) {
        int g = (g0 * 32 + gg + blockIdx.x) & 255;   // rotated start
        a += p4[(size_t)g * PP4 + j];
    }
    red[t] = a;
    __syncthreads();
    for (int s = 128; s >= 32; s >>= 1) {
        if (t < s) { red[t] += red[t + s]; sred[t] += sred[t + s]; }
        __syncthreads();
    }
    if (t < 32) {
        float sv = sred[t];
#pragma unroll
        for (int off = 16; off >= 1; off >>= 1) sv += __shfl_xor(sv, off);
        out[blockIdx.x * 32 + t] = red[t] / sv;
    }
}

// ---------------------------------------------------------------------------
extern "C" void kernel_launch(void* const* d_in, const int* in_sizes, int n_in,
                              void* d_out, int out_size, void* d_ws, size_t ws_size,
                              hipStream_t stream) {
    const float* X   = (const float*)d_in[0];   // [8192, 256]
    const float* adj = (const float*)d_in[1];   // [8192, 8192]
    const float* W   = (const float*)d_in[2];   // [256, 32]
    // d_in[3] = b: ignored — softmax over dim 0 is invariant to per-column shift.
    float* out = (float*)d_out;                 // [32, 256]

    char* w = (char*)d_ws;
    unsigned short* hi_frag = (unsigned short*)w;                        // 512 KB
    unsigned short* lo_frag = (unsigned short*)(w + 512 * 1024);         // 512 KB
    size_t off = 1024 * 1024;
    float* part = (float*)(w + off);        off += (size_t)4 * PPART * sizeof(float);
    float* logits_sum = (float*)(w + off);  off += (size_t)NN * DOUT * sizeof(float);
    float* Mpart = (float*)(w + off);       off += 256 * 32 * sizeof(float);
    float* Spart = (float*)(w + off);       off += 256 * 32 * sizeof(float);
    float* p4 = (float*)(w + off);          off += (size_t)256 * PP4 * sizeof(float);

    k1_support<<<NN / 32, 256, 0, stream>>>(X, W, hi_frag, lo_frag);
    k2_logits<<<dim3(NN / 32, 4), 512, 0, stream>>>(adj, hi_frag, lo_frag, part);
    t1_sum_max<<<256, 256, 0, stream>>>(part, logits_sum, Mpart);
    t2_exp_pool<<<256, 256, 0, stream>>>(logits_sum, Mpart, X, Spart, p4);
    t3_reduce<<<256, 256, 0, stream>>>(p4, Spart, out);
}

// Round 5
// 418.343 us; speedup vs baseline: 1.1746x; 1.0714x over previous
//
#include <hip/hip_runtime.h>
#include <stdint.h>

#define NN   8192
#define DIN  256
#define DOUT 32

#define PP4   (DOUT * DIN + 320)  // padded stride (floats) for pooling partials

typedef short bf16x8 __attribute__((ext_vector_type(8)));
typedef float f32x16 __attribute__((ext_vector_type(16)));

union BF8 { uint32_t u[4]; bf16x8 v; };

// Split fp32 pair into packed bf16 hi (truncated top 16 bits) and bf16 lo (residual).
__device__ __forceinline__ void split_pair(float a, float b, uint32_t& hp, uint32_t& lp) {
    uint32_t ua = __float_as_uint(a), ub = __float_as_uint(b);
    hp = (ua >> 16) | (ub & 0xffff0000u);
    float la = a - __uint_as_float(ua & 0xffff0000u);
    float lb = b - __uint_as_float(ub & 0xffff0000u);
    lp = (__float_as_uint(la) >> 16) | (__float_as_uint(lb) & 0xffff0000u);
}

// ---------------------------------------------------------------------------
// K1: support = X @ W (fp32 accumulate), emitted as bf16 hi/lo MFMA B-fragments.
// B-frag layout (v_mfma_f32_32x32x16_bf16): lane l holds B[k=(l>>5)*8+j][n=l&31].
__global__ __launch_bounds__(256) void k1_support(
    const float* __restrict__ X, const float* __restrict__ W,
    unsigned short* __restrict__ hi_frag, unsigned short* __restrict__ lo_frag)
{
    __shared__ float Xs[32 * 256];   // 32 KB
    int t = threadIdx.x;
    int kbase = blockIdx.x * 32;

    const float4* Xg = (const float4*)(X + (size_t)kbase * DIN);
    float4* Xs4 = (float4*)Xs;
#pragma unroll
    for (int p = 0; p < 8; ++p) Xs4[p * 256 + t] = Xg[p * 256 + t];
    __syncthreads();

    int c = t & 31;
    int q = t >> 5;
    int kb2  = q >> 2;
    int half = (q >> 1) & 1;
    int j4   = q & 1;
    int krow0 = kb2 * 16 + half * 8 + j4 * 4;

    float acc[4] = {0.f, 0.f, 0.f, 0.f};
    for (int d = 0; d < 256; ++d) {
        float w = W[d * 32 + c];
#pragma unroll
        for (int jj = 0; jj < 4; ++jj)
            acc[jj] += Xs[(krow0 + jj) * 256 + d] * w;
    }

    uint32_t h01, l01, h23, l23;
    split_pair(acc[0], acc[1], h01, l01);
    split_pair(acc[2], acc[3], h23, l23);

    int ks = (kbase >> 4) + kb2;
    size_t elembase = (size_t)ks * 512 + (size_t)(half * 32 + c) * 8 + j4 * 4;
    *(uint2*)(hi_frag + elembase) = make_uint2(h01, h23);
    *(uint2*)(lo_frag + elembase) = make_uint2(l01, l23);
}

// ---------------------------------------------------------------------------
// K2: partial logits via split-bf16 MFMA. R0's measured-best structure:
// direct-to-register adj loads, no LDS, no barriers, no atomics; each k-chunk
// (blockIdx.y of 16) writes its own 1 MB partial buffer.
__global__ __launch_bounds__(256) void k2_logits(
    const float* __restrict__ adj,
    const unsigned short* __restrict__ hi_frag,
    const unsigned short* __restrict__ lo_frag,
    float* __restrict__ part)     // [16][NN*DOUT]
{
    int t = threadIdx.x;
    int lane = t & 63, wv = t >> 6;
    int row_tile = blockIdx.x * 128 + wv * 32;
    int r  = lane & 31;
    int hs = lane >> 5;

    const float* arow = adj + (size_t)(row_tile + r) * NN + blockIdx.y * 512 + hs * 8;
    const unsigned short* hp = hi_frag + (size_t)blockIdx.y * 32 * 512 + lane * 8;
    const unsigned short* lp = lo_frag + (size_t)blockIdx.y * 32 * 512 + lane * 8;

    f32x16 acc;
#pragma unroll
    for (int i = 0; i < 16; ++i) acc[i] = 0.f;

#pragma unroll 4
    for (int s = 0; s < 32; ++s) {
        float4 a0 = *(const float4*)arow;
        float4 a1 = *(const float4*)(arow + 4);
        BF8 bh, bl, ah, al;
        bh.v = *(const bf16x8*)hp;
        bl.v = *(const bf16x8*)lp;
        split_pair(a0.x, a0.y, ah.u[0], al.u[0]);
        split_pair(a0.z, a0.w, ah.u[1], al.u[1]);
        split_pair(a1.x, a1.y, ah.u[2], al.u[2]);
        split_pair(a1.z, a1.w, ah.u[3], al.u[3]);
        acc = __builtin_amdgcn_mfma_f32_32x32x16_bf16(ah.v, bh.v, acc, 0, 0, 0);
        acc = __builtin_amdgcn_mfma_f32_32x32x16_bf16(ah.v, bl.v, acc, 0, 0, 0);
        acc = __builtin_amdgcn_mfma_f32_32x32x16_bf16(al.v, bh.v, acc, 0, 0, 0);
        arow += 16; hp += 512; lp += 512;
    }

    float* pdst = part + (size_t)blockIdx.y * (NN * DOUT);
    // D layout: col = lane&31, row = (reg&3) + 8*(reg>>2) + 4*(lane>>5)
#pragma unroll
    for (int reg = 0; reg < 16; ++reg) {
        int rt = (reg & 3) + 8 * (reg >> 2) + 4 * hs;
        pdst[(size_t)(row_tile + rt) * 32 + r] = acc[reg];
    }
}

// ---------------------------------------------------------------------------
// T1: sum the 16 k-partials -> logits_sum; per-block column maxes. 256 blocks.
// Element j of thread t's float4 lands in column (4t+j)&31 (thread-invariant).
__global__ __launch_bounds__(256) void t1_sum_max(
    const float* __restrict__ part, float* __restrict__ logits_sum,
    float* __restrict__ Mpart)     // [256][32]
{
    __shared__ float red[256 * 4];
    int t = threadIdx.x;
    size_t f = (size_t)blockIdx.x * 256 + t;   // float4 index

    float4 v = ((const float4*)part)[f];
#pragma unroll
    for (int p = 1; p < 16; ++p) {
        float4 u = ((const float4*)(part + (size_t)p * NN * DOUT))[f];
        v.x += u.x; v.y += u.y; v.z += u.z; v.w += u.w;
    }
    ((float4*)logits_sum)[f] = v;

    red[t * 4 + 0] = v.x; red[t * 4 + 1] = v.y;
    red[t * 4 + 2] = v.z; red[t * 4 + 3] = v.w;
    __syncthreads();
    for (int s = 128; s >= 8; s >>= 1) {
        if (t < s)
#pragma unroll
            for (int j = 0; j < 4; ++j)
                red[t * 4 + j] = fmaxf(red[t * 4 + j], red[(t + s) * 4 + j]);
        __syncthreads();
    }
    if (t < 8)
#pragma unroll
        for (int j = 0; j < 4; ++j)
            Mpart[blockIdx.x * 32 + t * 4 + j] = red[t * 4 + j];
}

// ---------------------------------------------------------------------------
// T2: fused exp + pooling. Fold global col maxes (redundantly per block),
// e = exp(logit - M) kept in regs/LDS (no e_buf round-trip), column sums
// -> Spart, then pool p4[b] = e^T @ X over this block's 32 rows. 256 blocks.
__global__ __launch_bounds__(256) void t2_exp_pool(
    const float* __restrict__ logits_sum, const float* __restrict__ Mpart,
    const float* __restrict__ X, float* __restrict__ Spart,
    float* __restrict__ p4)    // 256 partials, stride PP4 floats
{
    __shared__ float red[256 * 4];   // 4 KB reduction scratch
    __shared__ float As[32 * 32];    // 4 KB: exp(logit) for this block's rows
    __shared__ float Xs[8 * 256];    // 8 KB: X staging
    int t = threadIdx.x;
    int b = blockIdx.x;
    int c = t & 31, g0 = t >> 5;

    // fold global column maxes from Mpart (32 KB, L2-resident)
    {
        float m = -3.4e38f;
#pragma unroll
        for (int gg = 0; gg < 32; ++gg)
            m = fmaxf(m, Mpart[(g0 * 32 + gg) * 32 + c]);
        red[t] = m;
    }
    __syncthreads();
    for (int s = 128; s >= 32; s >>= 1) {
        if (t < s) red[t] = fmaxf(red[t], red[t + s]);
        __syncthreads();
    }
    float m0 = red[(4 * t + 0) & 31], m1 = red[(4 * t + 1) & 31];
    float m2 = red[(4 * t + 2) & 31], m3 = red[(4 * t + 3) & 31];
    __syncthreads();   // before red reuse

    size_t f = (size_t)b * 256 + t;
    float4 v = ((const float4*)logits_sum)[f];
    v.x = __expf(v.x - m0); v.y = __expf(v.y - m1);
    v.z = __expf(v.z - m2); v.w = __expf(v.w - m3);
    // scatter into As[row][col]: row = t>>3, cols = (4t+j)&31
    {
        int row = t >> 3, cb = (4 * t) & 31;
        As[row * 32 + cb]     = v.x;
        As[row * 32 + cb + 1] = v.y;
        As[row * 32 + cb + 2] = v.z;
        As[row * 32 + cb + 3] = v.w;
    }
    red[t * 4 + 0] = v.x; red[t * 4 + 1] = v.y;
    red[t * 4 + 2] = v.z; red[t * 4 + 3] = v.w;
    __syncthreads();
    for (int s = 128; s >= 8; s >>= 1) {
        if (t < s)
#pragma unroll
            for (int j = 0; j < 4; ++j)
                red[t * 4 + j] += red[(t + s) * 4 + j];
        __syncthreads();
    }
    if (t < 8)
#pragma unroll
        for (int j = 0; j < 4; ++j)
            Spart[b * 32 + t * 4 + j] = red[t * 4 + j];

    // pooling: p4[b] = e(32 rows)^T @ X(32 rows), X staged 8 rows at a time
    int dg = t >> 5;
    int ibase = b * 32;
    float acc[32];
#pragma unroll
    for (int i = 0; i < 32; ++i) acc[i] = 0.f;

    for (int rnd = 0; rnd < 4; ++rnd) {
        __syncthreads();
        const float4* Xg = (const float4*)(X + (size_t)(ibase + rnd * 8) * DIN);
        float4* Xs4 = (float4*)Xs;
        Xs4[t]       = Xg[t];
        Xs4[256 + t] = Xg[256 + t];
        __syncthreads();
#pragma unroll
        for (int i2 = 0; i2 < 8; ++i2) {
            float a = As[(rnd * 8 + i2) * 32 + c];
#pragma unroll
            for (int dd = 0; dd < 32; ++dd)
                acc[dd] += a * Xs[i2 * 256 + dg * 32 + dd];
        }
    }
    float* dst = p4 + (size_t)b * PP4 + (size_t)c * 256 + dg * 32;
#pragma unroll
    for (int q = 0; q < 8; ++q)
        ((float4*)dst)[q] = make_float4(acc[q * 4], acc[q * 4 + 1],
                                        acc[q * 4 + 2], acc[q * 4 + 3]);
}

// ---------------------------------------------------------------------------
// T3: reduce 256 pooling partials + total S, scale by 1/S[cluster] -> out.
__global__ __launch_bounds__(256) void t3_reduce(
    const float* __restrict__ p4, const float* __restrict__ Spart,
    float* __restrict__ out)
{
    __shared__ float red[256];
    __shared__ float sred[256];
    int t = threadIdx.x;
    int c_out = blockIdx.x >> 3;     // all 32 outputs of this block share one cluster

    sred[t] = Spart[t * 32 + c_out];

    int j = blockIdx.x * 32 + (t & 31);
    int g0 = t >> 5;
    float a = 0.f;
#pragma unroll
    for (int gg = 0; gg < 32; ++gg) {
        int g = (g0 * 32 + gg + blockIdx.x) & 255;   // rotated start
        a += p4[(size_t)g * PP4 + j];
    }
    red[t] = a;
    __syncthreads();
    for (int s = 128; s >= 32; s >>= 1) {
        if (t < s) { red[t] += red[t + s]; sred[t] += sred[t + s]; }
        __syncthreads();
    }
    if (t < 32) {
        float sv = sred[t];
#pragma unroll
        for (int off = 16; off >= 1; off >>= 1) sv += __shfl_xor(sv, off);
        out[blockIdx.x * 32 + t] = red[t] / sv;
    }
}

// ---------------------------------------------------------------------------
extern "C" void kernel_launch(void* const* d_in, const int* in_sizes, int n_in,
                              void* d_out, int out_size, void* d_ws, size_t ws_size,
                              hipStream_t stream) {
    const float* X   = (const float*)d_in[0];   // [8192, 256]
    const float* adj = (const float*)d_in[1];   // [8192, 8192]
    const float* W   = (const float*)d_in[2];   // [256, 32]
    // d_in[3] = b: ignored — softmax over dim 0 is invariant to per-column shift.
    float* out = (float*)d_out;                 // [32, 256]

    char* w = (char*)d_ws;
    unsigned short* hi_frag = (unsigned short*)w;                        // 512 KB
    unsigned short* lo_frag = (unsigned short*)(w + 512 * 1024);         // 512 KB
    size_t off = 1024 * 1024;
    float* part = (float*)(w + off);        off += (size_t)16 * NN * DOUT * sizeof(float);
    float* logits_sum = (float*)(w + off);  off += (size_t)NN * DOUT * sizeof(float);
    float* Mpart = (float*)(w + off);       off += 256 * 32 * sizeof(float);
    float* Spart = (float*)(w + off);       off += 256 * 32 * sizeof(float);
    float* p4 = (float*)(w + off);          off += (size_t)256 * PP4 * sizeof(float);

    k1_support<<<NN / 32, 256, 0, stream>>>(X, W, hi_frag, lo_frag);
    k2_logits<<<dim3(NN / 128, 16), 256, 0, stream>>>(adj, hi_frag, lo_frag, part);
    t1_sum_max<<<256, 256, 0, stream>>>(part, logits_sum, Mpart);
    t2_exp_pool<<<256, 256, 0, stream>>>(logits_sum, Mpart, X, Spart, p4);
    t3_reduce<<<256, 256, 0, stream>>>(p4, Spart, out);
}

// Round 6
// 416.152 us; speedup vs baseline: 1.1808x; 1.0053x over previous
//
#include <hip/hip_runtime.h>
#include <stdint.h>

#define NN   8192
#define DIN  256
#define DOUT 32

#define PP4   (DOUT * DIN + 320)  // padded stride (floats) for pooling partials

typedef short bf16x8 __attribute__((ext_vector_type(8)));
typedef float f32x16 __attribute__((ext_vector_type(16)));

union BF8 { uint32_t u[4]; bf16x8 v; };

// Split fp32 pair into packed bf16 hi (truncated top 16 bits) and bf16 lo (residual).
__device__ __forceinline__ void split_pair(float a, float b, uint32_t& hp, uint32_t& lp) {
    uint32_t ua = __float_as_uint(a), ub = __float_as_uint(b);
    hp = (ua >> 16) | (ub & 0xffff0000u);
    float la = a - __uint_as_float(ua & 0xffff0000u);
    float lb = b - __uint_as_float(ub & 0xffff0000u);
    lp = (__float_as_uint(la) >> 16) | (__float_as_uint(lb) & 0xffff0000u);
}

// ---------------------------------------------------------------------------
// K1: support = X @ W (fp32 accumulate), emitted as bf16 hi/lo MFMA B-fragments.
// B-frag layout (v_mfma_f32_32x32x16_bf16): lane l holds B[k=(l>>5)*8+j][n=l&31].
__global__ __launch_bounds__(256) void k1_support(
    const float* __restrict__ X, const float* __restrict__ W,
    unsigned short* __restrict__ hi_frag, unsigned short* __restrict__ lo_frag)
{
    __shared__ float Xs[32 * 256];   // 32 KB
    int t = threadIdx.x;
    int kbase = blockIdx.x * 32;

    const float4* Xg = (const float4*)(X + (size_t)kbase * DIN);
    float4* Xs4 = (float4*)Xs;
#pragma unroll
    for (int p = 0; p < 8; ++p) Xs4[p * 256 + t] = Xg[p * 256 + t];
    __syncthreads();

    int c = t & 31;
    int q = t >> 5;
    int kb2  = q >> 2;
    int half = (q >> 1) & 1;
    int j4   = q & 1;
    int krow0 = kb2 * 16 + half * 8 + j4 * 4;

    float acc[4] = {0.f, 0.f, 0.f, 0.f};
    for (int d = 0; d < 256; ++d) {
        float w = W[d * 32 + c];
#pragma unroll
        for (int jj = 0; jj < 4; ++jj)
            acc[jj] += Xs[(krow0 + jj) * 256 + d] * w;
    }

    uint32_t h01, l01, h23, l23;
    split_pair(acc[0], acc[1], h01, l01);
    split_pair(acc[2], acc[3], h23, l23);

    int ks = (kbase >> 4) + kb2;
    size_t elembase = (size_t)ks * 512 + (size_t)(half * 32 + c) * 8 + j4 * 4;
    *(uint2*)(hi_frag + elembase) = make_uint2(h01, h23);
    *(uint2*)(lo_frag + elembase) = make_uint2(l01, l23);
}

// ---------------------------------------------------------------------------
// K2: partial logits via split-bf16 MFMA. Same per-wave inner loop and total
// wave count as the verified R0/R5 structure (direct-to-register adj loads, 32
// k-steps/wave, 16 waves/CU), but 8 waves share one 32-row tile and split K:
// wave wv owns cols [y*4096 + wv*512, +512). One LDS reduction folds the 8
// per-wave accumulators -> only 2 k-partials total (was 16): -28 MB HBM.
__global__ __launch_bounds__(512) void k2_logits(
    const float* __restrict__ adj,
    const unsigned short* __restrict__ hi_frag,
    const unsigned short* __restrict__ lo_frag,
    float* __restrict__ part)     // [2][NN*DOUT]
{
    __shared__ float red[8 * 1088];   // 34 KB; 17-float lane stride -> conflict-free
    int t = threadIdx.x;
    int lane = t & 63, wv = t >> 6;
    int row0 = blockIdx.x * 32;
    int y = blockIdx.y;
    int r  = lane & 31;
    int hs = lane >> 5;

    const float* arow = adj + (size_t)(row0 + r) * NN + y * 4096 + wv * 512 + hs * 8;
    const unsigned short* hp = hi_frag + ((size_t)y * 256 + wv * 32) * 512 + lane * 8;
    const unsigned short* lp = lo_frag + ((size_t)y * 256 + wv * 32) * 512 + lane * 8;

    f32x16 acc;
#pragma unroll
    for (int i = 0; i < 16; ++i) acc[i] = 0.f;

#pragma unroll 4
    for (int s = 0; s < 32; ++s) {
        float4 a0 = *(const float4*)arow;
        float4 a1 = *(const float4*)(arow + 4);
        BF8 bh, bl, ah, al;
        bh.v = *(const bf16x8*)hp;
        bl.v = *(const bf16x8*)lp;
        split_pair(a0.x, a0.y, ah.u[0], al.u[0]);
        split_pair(a0.z, a0.w, ah.u[1], al.u[1]);
        split_pair(a1.x, a1.y, ah.u[2], al.u[2]);
        split_pair(a1.z, a1.w, ah.u[3], al.u[3]);
        acc = __builtin_amdgcn_mfma_f32_32x32x16_bf16(ah.v, bh.v, acc, 0, 0, 0);
        acc = __builtin_amdgcn_mfma_f32_32x32x16_bf16(ah.v, bl.v, acc, 0, 0, 0);
        acc = __builtin_amdgcn_mfma_f32_32x32x16_bf16(al.v, bh.v, acc, 0, 0, 0);
        arow += 16; hp += 512; lp += 512;
    }

    // fold the 8 per-wave k-slices (same 32x32 output tile) via LDS
#pragma unroll
    for (int g = 0; g < 16; ++g) red[wv * 1088 + lane * 17 + g] = acc[g];
    __syncthreads();

    // D layout: col = lane&31, row = (reg&3) + 8*(reg>>2) + 4*(lane>>5)
    float* pdst = part + (size_t)y * (NN * DOUT) + (size_t)row0 * 32;
    for (int a = t; a < 1024; a += 512) {
        int row = a >> 5, col = a & 31;
        int l = col + 32 * ((row >> 2) & 1);
        int g = (row & 3) | ((row >> 3) << 2);
        float ssum = 0.f;
#pragma unroll
        for (int w8 = 0; w8 < 8; ++w8) ssum += red[w8 * 1088 + l * 17 + g];
        pdst[a] = ssum;
    }
}

// ---------------------------------------------------------------------------
// T1: sum the 2 k-partials -> logits_sum; per-block column maxes. 256 blocks.
// Element j of thread t's float4 lands in column (4t+j)&31 (thread-invariant).
__global__ __launch_bounds__(256) void t1_sum_max(
    const float* __restrict__ part, float* __restrict__ logits_sum,
    float* __restrict__ Mpart)     // [256][32]
{
    __shared__ float red[256 * 4];
    int t = threadIdx.x;
    size_t f = (size_t)blockIdx.x * 256 + t;   // float4 index

    float4 v = ((const float4*)part)[f];
    {
        float4 u = ((const float4*)(part + (size_t)NN * DOUT))[f];
        v.x += u.x; v.y += u.y; v.z += u.z; v.w += u.w;
    }
    ((float4*)logits_sum)[f] = v;

    red[t * 4 + 0] = v.x; red[t * 4 + 1] = v.y;
    red[t * 4 + 2] = v.z; red[t * 4 + 3] = v.w;
    __syncthreads();
    for (int s = 128; s >= 8; s >>= 1) {
        if (t < s)
#pragma unroll
            for (int j = 0; j < 4; ++j)
                red[t * 4 + j] = fmaxf(red[t * 4 + j], red[(t + s) * 4 + j]);
        __syncthreads();
    }
    if (t < 8)
#pragma unroll
        for (int j = 0; j < 4; ++j)
            Mpart[blockIdx.x * 32 + t * 4 + j] = red[t * 4 + j];
}

// ---------------------------------------------------------------------------
// T2: fused exp + pooling. Fold global col maxes (redundantly per block),
// e = exp(logit - M) kept in regs/LDS (no e_buf round-trip), column sums
// -> Spart, then pool p4[b] = e^T @ X over this block's 32 rows. 256 blocks.
__global__ __launch_bounds__(256) void t2_exp_pool(
    const float* __restrict__ logits_sum, const float* __restrict__ Mpart,
    const float* __restrict__ X, float* __restrict__ Spart,
    float* __restrict__ p4)    // 256 partials, stride PP4 floats
{
    __shared__ float red[256 * 4];   // 4 KB reduction scratch
    __shared__ float As[32 * 32];    // 4 KB: exp(logit) for this block's rows
    __shared__ float Xs[8 * 256];    // 8 KB: X staging
    int t = threadIdx.x;
    int b = blockIdx.x;
    int c = t & 31, g0 = t >> 5;

    // fold global column maxes from Mpart (32 KB, L2-resident)
    {
        float m = -3.4e38f;
#pragma unroll
        for (int gg = 0; gg < 32; ++gg)
            m = fmaxf(m, Mpart[(g0 * 32 + gg) * 32 + c]);
        red[t] = m;
    }
    __syncthreads();
    for (int s = 128; s >= 32; s >>= 1) {
        if (t < s) red[t] = fmaxf(red[t], red[t + s]);
        __syncthreads();
    }
    float m0 = red[(4 * t + 0) & 31], m1 = red[(4 * t + 1) & 31];
    float m2 = red[(4 * t + 2) & 31], m3 = red[(4 * t + 3) & 31];
    __syncthreads();   // before red reuse

    size_t f = (size_t)b * 256 + t;
    float4 v = ((const float4*)logits_sum)[f];
    v.x = __expf(v.x - m0); v.y = __expf(v.y - m1);
    v.z = __expf(v.z - m2); v.w = __expf(v.w - m3);
    // scatter into As[row][col]: row = t>>3, cols = (4t+j)&31
    {
        int row = t >> 3, cb = (4 * t) & 31;
        As[row * 32 + cb]     = v.x;
        As[row * 32 + cb + 1] = v.y;
        As[row * 32 + cb + 2] = v.z;
        As[row * 32 + cb + 3] = v.w;
    }
    red[t * 4 + 0] = v.x; red[t * 4 + 1] = v.y;
    red[t * 4 + 2] = v.z; red[t * 4 + 3] = v.w;
    __syncthreads();
    for (int s = 128; s >= 8; s >>= 1) {
        if (t < s)
#pragma unroll
            for (int j = 0; j < 4; ++j)
                red[t * 4 + j] += red[(t + s) * 4 + j];
        __syncthreads();
    }
    if (t < 8)
#pragma unroll
        for (int j = 0; j < 4; ++j)
            Spart[b * 32 + t * 4 + j] = red[t * 4 + j];

    // pooling: p4[b] = e(32 rows)^T @ X(32 rows), X staged 8 rows at a time
    int dg = t >> 5;
    int ibase = b * 32;
    float acc[32];
#pragma unroll
    for (int i = 0; i < 32; ++i) acc[i] = 0.f;

    for (int rnd = 0; rnd < 4; ++rnd) {
        __syncthreads();
        const float4* Xg = (const float4*)(X + (size_t)(ibase + rnd * 8) * DIN);
        float4* Xs4 = (float4*)Xs;
        Xs4[t]       = Xg[t];
        Xs4[256 + t] = Xg[256 + t];
        __syncthreads();
#pragma unroll
        for (int i2 = 0; i2 < 8; ++i2) {
            float a = As[(rnd * 8 + i2) * 32 + c];
#pragma unroll
            for (int dd = 0; dd < 32; ++dd)
                acc[dd] += a * Xs[i2 * 256 + dg * 32 + dd];
        }
    }
    float* dst = p4 + (size_t)b * PP4 + (size_t)c * 256 + dg * 32;
#pragma unroll
    for (int q = 0; q < 8; ++q)
        ((float4*)dst)[q] = make_float4(acc[q * 4], acc[q * 4 + 1],
                                        acc[q * 4 + 2], acc[q * 4 + 3]);
}

// ---------------------------------------------------------------------------
// T3: reduce 256 pooling partials + total S, scale by 1/S[cluster] -> out.
__global__ __launch_bounds__(256) void t3_reduce(
    const float* __restrict__ p4, const float* __restrict__ Spart,
    float* __restrict__ out)
{
    __shared__ float red[256];
    __shared__ float sred[256];
    int t = threadIdx.x;
    int c_out = blockIdx.x >> 3;     // all 32 outputs of this block share one cluster

    sred[t] = Spart[t * 32 + c_out];

    int j = blockIdx.x * 32 + (t & 31);
    int g0 = t >> 5;
    float a = 0.f;
#pragma unroll
    for (int gg = 0; gg < 32; ++gg) {
        int g = (g0 * 32 + gg + blockIdx.x) & 255;   // rotated start
        a += p4[(size_t)g * PP4 + j];
    }
    red[t] = a;
    __syncthreads();
    for (int s = 128; s >= 32; s >>= 1) {
        if (t < s) { red[t] += red[t + s]; sred[t] += sred[t + s]; }
        __syncthreads();
    }
    if (t < 32) {
        float sv = sred[t];
#pragma unroll
        for (int off = 16; off >= 1; off >>= 1) sv += __shfl_xor(sv, off);
        out[blockIdx.x * 32 + t] = red[t] / sv;
    }
}

// ---------------------------------------------------------------------------
extern "C" void kernel_launch(void* const* d_in, const int* in_sizes, int n_in,
                              void* d_out, int out_size, void* d_ws, size_t ws_size,
                              hipStream_t stream) {
    const float* X   = (const float*)d_in[0];   // [8192, 256]
    const float* adj = (const float*)d_in[1];   // [8192, 8192]
    const float* W   = (const float*)d_in[2];   // [256, 32]
    // d_in[3] = b: ignored — softmax over dim 0 is invariant to per-column shift.
    float* out = (float*)d_out;                 // [32, 256]

    char* w = (char*)d_ws;
    unsigned short* hi_frag = (unsigned short*)w;                        // 512 KB
    unsigned short* lo_frag = (unsigned short*)(w + 512 * 1024);         // 512 KB
    size_t off = 1024 * 1024;
    float* part = (float*)(w + off);        off += (size_t)2 * NN * DOUT * sizeof(float);
    float* logits_sum = (float*)(w + off);  off += (size_t)NN * DOUT * sizeof(float);
    float* Mpart = (float*)(w + off);       off += 256 * 32 * sizeof(float);
    float* Spart = (float*)(w + off);       off += 256 * 32 * sizeof(float);
    float* p4 = (float*)(w + off);          off += (size_t)256 * PP4 * sizeof(float);

    k1_support<<<NN / 32, 256, 0, stream>>>(X, W, hi_frag, lo_frag);
    k2_logits<<<dim3(NN / 32, 2), 512, 0, stream>>>(adj, hi_frag, lo_frag, part);
    t1_sum_max<<<256, 256, 0, stream>>>(part, logits_sum, Mpart);
    t2_exp_pool<<<256, 256, 0, stream>>>(logits_sum, Mpart, X, Spart, p4);
    t3_reduce<<<256, 256, 0, stream>>>(p4, Spart, out);
}